// Round 1
// baseline (303.408 us; speedup 1.0000x reference)
//
#include <hip/hip_runtime.h>
#include <hip/hip_bf16.h>

// Problem constants (fixed by reference)
#define BSZ 2
#define SEQ 2048
#define NH 16
#define HD 64
#define DIM 1024
#define MROWS (BSZ*SEQ)   // 4096

typedef short v8s __attribute__((ext_vector_type(8)));
typedef float v4f __attribute__((ext_vector_type(4)));

__device__ __forceinline__ ushort f2b(float f) {
    // round-to-nearest-even f32 -> bf16 (finite inputs only)
    unsigned int u = __float_as_uint(f);
    unsigned int r = (u + 0x7fffu + ((u >> 16) & 1u)) >> 16;
    return (ushort)r;
}

// ---------------- cast f32 -> bf16 ----------------
__global__ void castk(const float* __restrict__ s, ushort* __restrict__ d, int n) {
    int i4 = blockIdx.x * 256 + threadIdx.x;
    int i = i4 * 4;
    if (i < n) {
        float4 v = *reinterpret_cast<const float4*>(s + i);
        ushort4 o;
        o.x = f2b(v.x); o.y = f2b(v.y); o.z = f2b(v.z); o.w = f2b(v.w);
        *reinterpret_cast<ushort4*>(d + i) = o;
    }
}

// ---------------- bf16 GEMM: C[M,N] = A[M,K] @ Bw[N,K]^T ----------------
// MODE 0: store bf16 at [m*N+n], scaled
// MODE 1: store bf16 V-transposed: ((b*NH+h)*HD+d)*SEQ + s  (m=b*SEQ+s, n=h*HD+d)
// MODE 2: store f32 at [m*N+n]
#define GP 72  // padded LDS row stride (bf16 elems): 64+8, keeps 16B alignment

template<int MODE>
__global__ __launch_bounds__(256) void gemm_bt(const ushort* __restrict__ A,
                                               const ushort* __restrict__ Bw,
                                               void* __restrict__ Cout,
                                               int M, int N, int K, float scale) {
    __shared__ __align__(16) ushort As[64 * GP];
    __shared__ __align__(16) ushort Bs[64 * GP];
    const int bm = blockIdx.x, bn = blockIdx.y;
    const int t = threadIdx.x;
    const int w = t >> 6, l = t & 63;
    const int wr = w >> 1, wc = w & 1;   // wave computes 32x32 at (wr*32, wc*32)

    v4f acc[2][2];
    for (int i = 0; i < 2; i++) for (int j = 0; j < 2; j++) acc[i][j] = (v4f){0.f,0.f,0.f,0.f};

    for (int k0 = 0; k0 < K; k0 += 64) {
        __syncthreads();
        // stage 64x64 bf16 tiles of A and Bw (512 x 16B chunks each)
        for (int c = 0; c < 2; c++) {
            int id = t + c * 256;
            int row = id >> 3, ch = id & 7;
            *reinterpret_cast<uint4*>(&As[row * GP + ch * 8]) =
                *reinterpret_cast<const uint4*>(A + (size_t)(bm * 64 + row) * K + k0 + ch * 8);
            *reinterpret_cast<uint4*>(&Bs[row * GP + ch * 8]) =
                *reinterpret_cast<const uint4*>(Bw + (size_t)(bn * 64 + row) * K + k0 + ch * 8);
        }
        __syncthreads();
        for (int ks = 0; ks < 64; ks += 32) {
            v8s af[2], bf[2];
            for (int i = 0; i < 2; i++) {
                int ar = wr * 32 + i * 16 + (l & 15);
                af[i] = *reinterpret_cast<const v8s*>(&As[ar * GP + ks + (l >> 4) * 8]);
                int br = wc * 32 + i * 16 + (l & 15);
                bf[i] = *reinterpret_cast<const v8s*>(&Bs[br * GP + ks + (l >> 4) * 8]);
            }
            for (int i = 0; i < 2; i++)
                for (int j = 0; j < 2; j++)
                    acc[i][j] = __builtin_amdgcn_mfma_f32_16x16x32_bf16(af[i], bf[j], acc[i][j], 0, 0, 0);
        }
    }
    // C/D layout: col = lane&15, row = (lane>>4)*4 + r
    for (int i = 0; i < 2; i++)
        for (int j = 0; j < 2; j++)
            for (int r = 0; r < 4; r++) {
                int m = bm * 64 + wr * 32 + i * 16 + (l >> 4) * 4 + r;
                int n = bn * 64 + wc * 32 + j * 16 + (l & 15);
                float v = acc[i][j][r] * scale;
                if (MODE == 0) {
                    ((ushort*)Cout)[(size_t)m * N + n] = f2b(v);
                } else if (MODE == 1) {
                    int b = m >> 11, s = m & 2047, h = n >> 6, d = n & 63;
                    ((ushort*)Cout)[((size_t)(b * NH + h) * HD + d) * SEQ + s] = f2b(v);
                } else {
                    ((float*)Cout)[(size_t)m * N + n] = v;
                }
            }
}

// ---------------- flash attention ----------------
// Q,K: bf16 [B,S,H,D]; Vt: bf16 [B,H,D,S]; bias f32 [B,H,S,S]; mask f32 [S,S]
// O: bf16 [B,S,H,D]
__global__ __launch_bounds__(256) void attn_kernel(const ushort* __restrict__ Q,
                                                   const ushort* __restrict__ Kb,
                                                   const ushort* __restrict__ Vt,
                                                   const float* __restrict__ bias,
                                                   const float* __restrict__ mask,
                                                   ushort* __restrict__ O) {
    __shared__ __align__(16) ushort Ks[64 * GP];
    __shared__ __align__(16) ushort Vs[64 * GP];
    __shared__ __align__(16) ushort Ps[4][16 * GP];

    const int bh = blockIdx.x;          // b*NH + h
    const int qblk = blockIdx.y;        // 64 q-rows per block
    const int b = bh >> 4, h = bh & 15;
    const int t = threadIdx.x;
    const int w = t >> 6, l = t & 63;
    const int q0 = qblk * 64 + w * 16;  // this wave's 16 q rows

    // Q fragments (A operand): row = lane&15, k(d) = d0*32 + (lane>>4)*8 + j
    v8s qf[2];
    for (int d0 = 0; d0 < 2; d0++) {
        int q = q0 + (l & 15);
        int d = d0 * 32 + (l >> 4) * 8;
        qf[d0] = *reinterpret_cast<const v8s*>(&Q[((size_t)(b * SEQ + q) * NH + h) * HD + d]);
    }

    float m_r[4], l_r[4];
    v4f oacc[4];
    for (int r = 0; r < 4; r++) { m_r[r] = -1e30f; l_r[r] = 0.f; }
    for (int dt = 0; dt < 4; dt++) oacc[dt] = (v4f){0.f,0.f,0.f,0.f};

    const float* biasbh = bias + (size_t)bh * SEQ * SEQ;

    for (int k0 = 0; k0 < SEQ; k0 += 64) {
        __syncthreads();
        // stage K tile [64 s][64 d] and Vt tile [64 d][64 s-chunk]
        for (int c = 0; c < 2; c++) {
            int id = t + c * 256;
            int row = id >> 3, ch = id & 7;
            *reinterpret_cast<uint4*>(&Ks[row * GP + ch * 8]) =
                *reinterpret_cast<const uint4*>(&Kb[((size_t)(b * SEQ + k0 + row) * NH + h) * HD + ch * 8]);
            *reinterpret_cast<uint4*>(&Vs[row * GP + ch * 8]) =
                *reinterpret_cast<const uint4*>(&Vt[((size_t)bh * HD + row) * SEQ + k0 + ch * 8]);
        }
        __syncthreads();

        // QK^T: S[16 q][64 kcol] as 4 col-subtiles
        v4f sacc[4];
        for (int nt = 0; nt < 4; nt++) sacc[nt] = (v4f){0.f,0.f,0.f,0.f};
        for (int nt = 0; nt < 4; nt++)
            for (int d0 = 0; d0 < 2; d0++) {
                v8s kf = *reinterpret_cast<const v8s*>(&Ks[(nt * 16 + (l & 15)) * GP + d0 * 32 + (l >> 4) * 8]);
                sacc[nt] = __builtin_amdgcn_mfma_f32_16x16x32_bf16(qf[d0], kf, sacc[nt], 0, 0, 0);
            }

        // scores + bias + mask, online softmax (row r -> q = q0 + (l>>4)*4 + r)
        float p[4][4];
        for (int r = 0; r < 4; r++) {
            int q = q0 + (l >> 4) * 4 + r;
            const float* br_ = biasbh + (size_t)q * SEQ + k0;
            const float* mr_ = mask + (size_t)q * SEQ + k0;
            float mx = -1e30f;
            for (int nt = 0; nt < 4; nt++) {
                float s = sacc[nt][r] + br_[nt * 16 + (l & 15)] + mr_[nt * 16 + (l & 15)];
                p[nt][r] = s;
                mx = fmaxf(mx, s);
            }
            mx = fmaxf(mx, __shfl_xor(mx, 1));
            mx = fmaxf(mx, __shfl_xor(mx, 2));
            mx = fmaxf(mx, __shfl_xor(mx, 4));
            mx = fmaxf(mx, __shfl_xor(mx, 8));
            float mnew = fmaxf(m_r[r], mx);
            float corr = __expf(m_r[r] - mnew);
            m_r[r] = mnew;
            float rs = 0.f;
            for (int nt = 0; nt < 4; nt++) {
                float e = __expf(p[nt][r] - mnew);
                p[nt][r] = e;
                rs += e;
            }
            rs += __shfl_xor(rs, 1);
            rs += __shfl_xor(rs, 2);
            rs += __shfl_xor(rs, 4);
            rs += __shfl_xor(rs, 8);
            l_r[r] = l_r[r] * corr + rs;
            for (int dt = 0; dt < 4; dt++) oacc[dt][r] *= corr;
        }

        // store P (bf16) to wave-private LDS, transposing C-layout -> A-frag layout
        for (int r = 0; r < 4; r++) {
            int row = (l >> 4) * 4 + r;
            for (int nt = 0; nt < 4; nt++)
                Ps[w][row * GP + nt * 16 + (l & 15)] = f2b(p[nt][r]);
        }
        __syncthreads();

        // PV: O[16 q][64 d] += P[16][64] @ V[64][64]
        for (int c0 = 0; c0 < 2; c0++) {
            v8s pf = *reinterpret_cast<const v8s*>(&Ps[w][(l & 15) * GP + c0 * 32 + (l >> 4) * 8]);
            for (int dt = 0; dt < 4; dt++) {
                v8s vf = *reinterpret_cast<const v8s*>(&Vs[(dt * 16 + (l & 15)) * GP + c0 * 32 + (l >> 4) * 8]);
                oacc[dt] = __builtin_amdgcn_mfma_f32_16x16x32_bf16(pf, vf, oacc[dt], 0, 0, 0);
            }
        }
    }

    // normalize and store O (bf16 [B,S,H,D])
    for (int dt = 0; dt < 4; dt++)
        for (int r = 0; r < 4; r++) {
            int q = q0 + (l >> 4) * 4 + r;
            float v = oacc[dt][r] / l_r[r];
            O[((size_t)(b * SEQ + q) * NH + h) * HD + dt * 16 + (l & 15)] = f2b(v);
        }
}

extern "C" void kernel_launch(void* const* d_in, const int* in_sizes, int n_in,
                              void* d_out, int out_size, void* d_ws, size_t ws_size,
                              hipStream_t stream) {
    (void)in_sizes; (void)n_in; (void)out_size; (void)ws_size;
    const float* x    = (const float*)d_in[0];
    const float* mask = (const float*)d_in[1];
    const float* bias = (const float*)d_in[2];
    const float* wq   = (const float*)d_in[3];
    const float* wk   = (const float*)d_in[4];
    const float* wv   = (const float*)d_in[5];
    const float* wo   = (const float*)d_in[6];
    float* out = (float*)d_out;

    ushort* xb  = (ushort*)d_ws;          // 4M
    ushort* wqb = xb  + 4194304;          // 1M
    ushort* wkb = wqb + 1048576;
    ushort* wvb = wkb + 1048576;
    ushort* wob = wvb + 1048576;
    ushort* qb  = wob + 1048576;          // 4M
    ushort* kb  = qb  + 4194304;          // 4M
    ushort* vtb = kb  + 4194304;          // 4M
    ushort* ob  = vtb + 4194304;          // 4M  (total 48 MB)

    castk<<<4096, 256, 0, stream>>>(x,  xb,  4194304);
    castk<<<1024, 256, 0, stream>>>(wq, wqb, 1048576);
    castk<<<1024, 256, 0, stream>>>(wk, wkb, 1048576);
    castk<<<1024, 256, 0, stream>>>(wv, wvb, 1048576);
    castk<<<1024, 256, 0, stream>>>(wo, wob, 1048576);

    // Q gets the 1/sqrt(HD) scale folded in
    gemm_bt<0><<<dim3(64, 16), 256, 0, stream>>>(xb, wqb, qb,  MROWS, DIM, DIM, 0.125f);
    gemm_bt<0><<<dim3(64, 16), 256, 0, stream>>>(xb, wkb, kb,  MROWS, DIM, DIM, 1.0f);
    gemm_bt<1><<<dim3(64, 16), 256, 0, stream>>>(xb, wvb, vtb, MROWS, DIM, DIM, 1.0f);

    attn_kernel<<<dim3(32, 32), 256, 0, stream>>>(qb, kb, vtb, bias, mask, ob);

    gemm_bt<2><<<dim3(64, 16), 256, 0, stream>>>(ob, wob, out, MROWS, DIM, DIM, 1.0f);
}

// Round 2
// 294.666 us; speedup vs baseline: 1.0297x; 1.0297x over previous
//
#include <hip/hip_runtime.h>
#include <hip/hip_bf16.h>

#define BSZ 2
#define SEQ 2048
#define NH 16
#define HD 64
#define DIM 1024
#define MROWS (BSZ*SEQ)   // 4096

typedef short v8s __attribute__((ext_vector_type(8)));
typedef float v4f __attribute__((ext_vector_type(4)));

__device__ __forceinline__ ushort f2b(float f) {
    unsigned int u = __float_as_uint(f);
    unsigned int r = (u + 0x7fffu + ((u >> 16) & 1u)) >> 16;
    return (ushort)r;
}

__device__ __forceinline__ unsigned pk2(float lo, float hi) {
    unsigned r;
    asm("v_cvt_pk_bf16_f32 %0, %1, %2" : "=v"(r) : "v"(lo), "v"(hi));
    return r;
}

__device__ __forceinline__ void gld16(const void* g, void* l) {
    __builtin_amdgcn_global_load_lds((const __attribute__((address_space(1))) void*)g,
                                     (__attribute__((address_space(3))) void*)l, 16, 0, 0);
}

// ---------------- casts ----------------
__global__ void castx(const float* __restrict__ s, ushort* __restrict__ d, int n) {
    int i = (blockIdx.x * 256 + threadIdx.x) * 4;
    if (i < n) {
        float4 v = *reinterpret_cast<const float4*>(s + i);
        ushort4 o;
        o.x = f2b(v.x); o.y = f2b(v.y); o.z = f2b(v.z); o.w = f2b(v.w);
        *reinterpret_cast<ushort4*>(d + i) = o;
    }
}

// pack wq|wk|wv|wo (each [1024][1024] f32) into one bf16 [4096][1024]
__global__ void castw(const float* __restrict__ wq, const float* __restrict__ wk,
                      const float* __restrict__ wv, const float* __restrict__ wo,
                      ushort* __restrict__ dst) {
    int i = (blockIdx.x * 256 + threadIdx.x) * 4;   // 0..4M-1, block-uniform source
    const float* s; int off;
    if (i < (1 << 20))      { s = wq; off = 0; }
    else if (i < (2 << 20)) { s = wk; off = 1 << 20; }
    else if (i < (3 << 20)) { s = wv; off = 2 << 20; }
    else                    { s = wo; off = 3 << 20; }
    float4 v = *reinterpret_cast<const float4*>(s + (i - off));
    ushort4 o;
    o.x = f2b(v.x); o.y = f2b(v.y); o.z = f2b(v.z); o.w = f2b(v.w);
    *reinterpret_cast<ushort4*>(dst + i) = o;
}

// ---------------- 128x128 GEMM (m97 structure): C = A[4096,1024] @ Bw[N,1024]^T
// MODE 0: fused QKV (N=3072): region by bn>>3 -> Q (scaled, bf16), K (bf16), V (bf16 transposed [B,H,D,S])
// MODE 1: f32 out [4096,1024]
template<int MODE>
__global__ __launch_bounds__(256) void gemm128(const ushort* __restrict__ A,
                                               const ushort* __restrict__ Bw,
                                               ushort* __restrict__ oq,
                                               ushort* __restrict__ ok,
                                               ushort* __restrict__ ov,
                                               float* __restrict__ of) {
    __shared__ __align__(16) ushort As[128 * 64];
    __shared__ __align__(16) ushort Bs[128 * 64];
    const int bm = blockIdx.x, bn = blockIdx.y;
    const int t = threadIdx.x;
    const int w = t >> 6, l = t & 63;
    const int g = l >> 4, lr = l & 15;
    const int wr = w >> 1, wc = w & 1;

    v4f acc[4][4];
    #pragma unroll
    for (int i = 0; i < 4; i++)
        #pragma unroll
        for (int j = 0; j < 4; j++) acc[i][j] = (v4f){0.f, 0.f, 0.f, 0.f};

    for (int kt = 0; kt < 16; ++kt) {
        const int k0 = kt * 64;
        __syncthreads();
        #pragma unroll
        for (int i = 0; i < 4; ++i) {
            int c = i * 256 + t;
            int row = c >> 3, cc = c & 7;
            gld16(A  + (size_t)(bm * 128 + row) * 1024 + k0 + cc * 8,
                  (ushort*)As + (i * 256 + w * 64) * 8);
            gld16(Bw + (size_t)(bn * 128 + row) * 1024 + k0 + cc * 8,
                  (ushort*)Bs + (i * 256 + w * 64) * 8);
        }
        __syncthreads();
        #pragma unroll
        for (int ks = 0; ks < 64; ks += 32) {
            v8s af[4], bf[4];
            #pragma unroll
            for (int i = 0; i < 4; i++) {
                af[i] = *reinterpret_cast<const v8s*>(&As[(wr * 64 + i * 16 + lr) * 64 + ks + g * 8]);
                bf[i] = *reinterpret_cast<const v8s*>(&Bs[(wc * 64 + i * 16 + lr) * 64 + ks + g * 8]);
            }
            #pragma unroll
            for (int i = 0; i < 4; i++)
                #pragma unroll
                for (int j = 0; j < 4; j++)
                    acc[i][j] = __builtin_amdgcn_mfma_f32_16x16x32_bf16(af[i], bf[j], acc[i][j], 0, 0, 0);
        }
    }

    if (MODE == 0) {
        const int region = bn >> 3;           // 0=Q 1=K 2=V
        const float scale = (region == 0) ? 0.125f : 1.0f;
        #pragma unroll
        for (int i = 0; i < 4; i++) {
            int m0 = bm * 128 + wr * 64 + i * 16 + g * 4;
            #pragma unroll
            for (int j = 0; j < 4; j++) {
                int nl = (bn & 7) * 128 + wc * 64 + j * 16 + lr;
                if (region == 2) {
                    int bb = m0 >> 11, s0 = m0 & 2047;
                    int hh = nl >> 6, dd = nl & 63;
                    ushort4 o4;
                    o4.x = f2b(acc[i][j][0]); o4.y = f2b(acc[i][j][1]);
                    o4.z = f2b(acc[i][j][2]); o4.w = f2b(acc[i][j][3]);
                    *reinterpret_cast<ushort4*>(&ov[((size_t)(bb * NH + hh) * HD + dd) * SEQ + s0]) = o4;
                } else {
                    ushort* dst = (region == 0) ? oq : ok;
                    #pragma unroll
                    for (int r = 0; r < 4; r++)
                        dst[(size_t)(m0 + r) * 1024 + nl] = f2b(acc[i][j][r] * scale);
                }
            }
        }
    } else {
        #pragma unroll
        for (int i = 0; i < 4; i++) {
            int m0 = bm * 128 + wr * 64 + i * 16 + g * 4;
            #pragma unroll
            for (int j = 0; j < 4; j++) {
                int n = bn * 128 + wc * 64 + j * 16 + lr;
                #pragma unroll
                for (int r = 0; r < 4; r++)
                    of[(size_t)(m0 + r) * 1024 + n] = acc[i][j][r];
            }
        }
    }
}

// ---------------- flash attention, swapped QK^T ----------------
// Q,K: bf16 [B,S,H,D]; Vt: bf16 [B,H,D,S]; bias f32 [B,H,S,S]; mask f32 [S,S]
// Each lane owns ONE q row (q = q0 + (l&15)); lane group g=(l>>4) owns k-chunks.
#define GP 72
__global__ __launch_bounds__(256) void attn_kernel(const ushort* __restrict__ Q,
                                                   const ushort* __restrict__ Kb,
                                                   const ushort* __restrict__ Vt,
                                                   const float* __restrict__ bias,
                                                   const float* __restrict__ mask,
                                                   ushort* __restrict__ O) {
    __shared__ __align__(16) ushort Ks[64 * GP];
    __shared__ __align__(16) ushort Vs[64 * GP];
    __shared__ __align__(16) ushort Ps[4][16 * GP];

    const int bh = blockIdx.x, qblk = blockIdx.y;
    const int b = bh >> 4, h = bh & 15;
    const int t = threadIdx.x, w = t >> 6, l = t & 63;
    const int lr = l & 15, g = l >> 4;
    const int qg = qblk * 64 + w * 16 + lr;

    // Q fragment (B operand): lane holds Q[qg][d0*32 + g*8 .. +8]
    v8s qf[2];
    #pragma unroll
    for (int d0 = 0; d0 < 2; ++d0)
        qf[d0] = *reinterpret_cast<const v8s*>(&Q[((size_t)(b * SEQ + qg) * NH + h) * HD + d0 * 32 + g * 8]);

    float m_run = -1e30f, l_run = 0.f;
    v4f oacc[4];   // oacc[dt][r] = O^T[d = dt*16 + g*4 + r][qg]
    #pragma unroll
    for (int dt = 0; dt < 4; ++dt) oacc[dt] = (v4f){0.f, 0.f, 0.f, 0.f};

    const float* bp = bias + (size_t)bh * SEQ * SEQ + (size_t)qg * SEQ;
    const float* mp = mask + (size_t)qg * SEQ;

    for (int k0 = 0; k0 < SEQ; k0 += 64) {
        __syncthreads();
        #pragma unroll
        for (int c = 0; c < 2; ++c) {
            int id = t + c * 256;
            int row = id >> 3, ch = id & 7;
            *reinterpret_cast<uint4*>(&Ks[row * GP + ch * 8]) =
                *reinterpret_cast<const uint4*>(&Kb[((size_t)(b * SEQ + k0 + row) * NH + h) * HD + ch * 8]);
            *reinterpret_cast<uint4*>(&Vs[row * GP + ch * 8]) =
                *reinterpret_cast<const uint4*>(&Vt[((size_t)bh * HD + row) * SEQ + k0 + ch * 8]);
        }
        __syncthreads();

        // swapped QK^T: sacc[nt][r] = S[k0 + nt*16 + g*4 + r][qg]
        v4f sacc[4];
        #pragma unroll
        for (int nt = 0; nt < 4; ++nt) sacc[nt] = (v4f){0.f, 0.f, 0.f, 0.f};
        __builtin_amdgcn_s_setprio(1);
        #pragma unroll
        for (int nt = 0; nt < 4; ++nt)
            #pragma unroll
            for (int d0 = 0; d0 < 2; ++d0) {
                v8s kf = *reinterpret_cast<const v8s*>(&Ks[(nt * 16 + lr) * GP + d0 * 32 + g * 8]);
                sacc[nt] = __builtin_amdgcn_mfma_f32_16x16x32_bf16(kf, qf[d0], sacc[nt], 0, 0, 0);
            }
        __builtin_amdgcn_s_setprio(0);

        // scores + bias + mask (float4 loads), in-lane online softmax
        float p[4][4];
        float mx = -1e30f;
        #pragma unroll
        for (int nt = 0; nt < 4; ++nt) {
            float4 bv = *reinterpret_cast<const float4*>(bp + k0 + nt * 16 + g * 4);
            float4 mv = *reinterpret_cast<const float4*>(mp + k0 + nt * 16 + g * 4);
            p[nt][0] = sacc[nt][0] + bv.x + mv.x;
            p[nt][1] = sacc[nt][1] + bv.y + mv.y;
            p[nt][2] = sacc[nt][2] + bv.z + mv.z;
            p[nt][3] = sacc[nt][3] + bv.w + mv.w;
            mx = fmaxf(mx, fmaxf(fmaxf(p[nt][0], p[nt][1]), fmaxf(p[nt][2], p[nt][3])));
        }
        mx = fmaxf(mx, __shfl_xor(mx, 16));
        mx = fmaxf(mx, __shfl_xor(mx, 32));
        float mnew = fmaxf(m_run, mx);
        float corr = __expf(m_run - mnew);
        m_run = mnew;
        float rs = 0.f;
        #pragma unroll
        for (int nt = 0; nt < 4; ++nt)
            #pragma unroll
            for (int r = 0; r < 4; ++r) {
                float e = __expf(p[nt][r] - mnew);
                p[nt][r] = e;
                rs += e;
            }
        rs += __shfl_xor(rs, 16);
        rs += __shfl_xor(rs, 32);
        l_run = l_run * corr + rs;
        #pragma unroll
        for (int dt = 0; dt < 4; ++dt) oacc[dt] *= corr;

        // P -> bf16 pairs into wave-private LDS row qg (no barrier needed)
        #pragma unroll
        for (int nt = 0; nt < 4; ++nt) {
            unsigned lo = pk2(p[nt][0], p[nt][1]);
            unsigned hi = pk2(p[nt][2], p[nt][3]);
            *reinterpret_cast<unsigned*>(&Ps[w][lr * GP + nt * 16 + g * 4])     = lo;
            *reinterpret_cast<unsigned*>(&Ps[w][lr * GP + nt * 16 + g * 4 + 2]) = hi;
        }

        // PV: O^T[d][q] += V^T[d][k] * P[k][q]
        __builtin_amdgcn_s_setprio(1);
        #pragma unroll
        for (int c0 = 0; c0 < 2; ++c0) {
            v8s pf = *reinterpret_cast<const v8s*>(&Ps[w][lr * GP + c0 * 32 + g * 8]);
            #pragma unroll
            for (int dt = 0; dt < 4; ++dt) {
                v8s vf = *reinterpret_cast<const v8s*>(&Vs[(dt * 16 + lr) * GP + c0 * 32 + g * 8]);
                oacc[dt] = __builtin_amdgcn_mfma_f32_16x16x32_bf16(vf, pf, oacc[dt], 0, 0, 0);
            }
        }
        __builtin_amdgcn_s_setprio(0);
    }

    float inv = 1.f / l_run;
    #pragma unroll
    for (int dt = 0; dt < 4; ++dt) {
        ushort4 o4;
        o4.x = f2b(oacc[dt][0] * inv); o4.y = f2b(oacc[dt][1] * inv);
        o4.z = f2b(oacc[dt][2] * inv); o4.w = f2b(oacc[dt][3] * inv);
        *reinterpret_cast<ushort4*>(&O[((size_t)(b * SEQ + qg) * NH + h) * HD + dt * 16 + g * 4]) = o4;
    }
}

extern "C" void kernel_launch(void* const* d_in, const int* in_sizes, int n_in,
                              void* d_out, int out_size, void* d_ws, size_t ws_size,
                              hipStream_t stream) {
    (void)in_sizes; (void)n_in; (void)out_size; (void)ws_size;
    const float* x    = (const float*)d_in[0];
    const float* mask = (const float*)d_in[1];
    const float* bias = (const float*)d_in[2];
    const float* wq   = (const float*)d_in[3];
    const float* wk   = (const float*)d_in[4];
    const float* wv   = (const float*)d_in[5];
    const float* wo   = (const float*)d_in[6];
    float* out = (float*)d_out;

    ushort* xb    = (ushort*)d_ws;           // 4M elems
    ushort* wcomb = xb    + (4 << 20);       // 4M  (wq|wk|wv|wo rows)
    ushort* qb    = wcomb + (4 << 20);       // 4M
    ushort* kb    = qb    + (4 << 20);       // 4M
    ushort* vtb   = kb    + (4 << 20);       // 4M
    ushort* ob    = vtb   + (4 << 20);       // 4M   total 48 MB

    castx<<<4096, 256, 0, stream>>>(x, xb, 1 << 22);
    castw<<<4096, 256, 0, stream>>>(wq, wk, wv, wo, wcomb);

    gemm128<0><<<dim3(32, 24), 256, 0, stream>>>(xb, wcomb, qb, kb, vtb, nullptr);

    attn_kernel<<<dim3(32, 32), 256, 0, stream>>>(qb, kb, vtb, bias, mask, ob);

    gemm128<1><<<dim3(32, 8), 256, 0, stream>>>(ob, wcomb + (size_t)3072 * 1024,
                                                nullptr, nullptr, nullptr, out);
}

// Round 3
// 288.858 us; speedup vs baseline: 1.0504x; 1.0201x over previous
//
#include <hip/hip_runtime.h>
#include <hip/hip_bf16.h>

#define BSZ 2
#define SEQ 2048
#define NH 16
#define HD 64
#define DIM 1024
#define MROWS (BSZ*SEQ)   // 4096

typedef short v8s __attribute__((ext_vector_type(8)));
typedef float v4f __attribute__((ext_vector_type(4)));

__device__ __forceinline__ ushort f2b(float f) {
    unsigned int u = __float_as_uint(f);
    unsigned int r = (u + 0x7fffu + ((u >> 16) & 1u)) >> 16;
    return (ushort)r;
}

__device__ __forceinline__ unsigned pk2(float lo, float hi) {
    unsigned r;
    asm("v_cvt_pk_bf16_f32 %0, %1, %2" : "=v"(r) : "v"(lo), "v"(hi));
    return r;
}

__device__ __forceinline__ void gld16(const void* g, void* l) {
    __builtin_amdgcn_global_load_lds((const __attribute__((address_space(1))) void*)g,
                                     (__attribute__((address_space(3))) void*)l, 16, 0, 0);
}

// ---------------- casts ----------------
__global__ void castx(const float* __restrict__ s, ushort* __restrict__ d, int n) {
    int i = (blockIdx.x * 256 + threadIdx.x) * 4;
    if (i < n) {
        float4 v = *reinterpret_cast<const float4*>(s + i);
        ushort4 o;
        o.x = f2b(v.x); o.y = f2b(v.y); o.z = f2b(v.z); o.w = f2b(v.w);
        *reinterpret_cast<ushort4*>(d + i) = o;
    }
}

__global__ void castw(const float* __restrict__ wq, const float* __restrict__ wk,
                      const float* __restrict__ wv, const float* __restrict__ wo,
                      ushort* __restrict__ dst) {
    int i = (blockIdx.x * 256 + threadIdx.x) * 4;
    const float* s; int off;
    if (i < (1 << 20))      { s = wq; off = 0; }
    else if (i < (2 << 20)) { s = wk; off = 1 << 20; }
    else if (i < (3 << 20)) { s = wv; off = 2 << 20; }
    else                    { s = wo; off = 3 << 20; }
    float4 v = *reinterpret_cast<const float4*>(s + (i - off));
    ushort4 o;
    o.x = f2b(v.x); o.y = f2b(v.y); o.z = f2b(v.z); o.w = f2b(v.w);
    *reinterpret_cast<ushort4*>(dst + i) = o;
}

// ---------------- 128x128 GEMM (m97 structure): C = A[4096,1024] @ Bw[N,1024]^T
template<int MODE>
__global__ __launch_bounds__(256) void gemm128(const ushort* __restrict__ A,
                                               const ushort* __restrict__ Bw,
                                               ushort* __restrict__ oq,
                                               ushort* __restrict__ ok,
                                               ushort* __restrict__ ov,
                                               float* __restrict__ of) {
    __shared__ __align__(16) ushort As[128 * 64];
    __shared__ __align__(16) ushort Bs[128 * 64];
    const int bm = blockIdx.x, bn = blockIdx.y;
    const int t = threadIdx.x;
    const int w = t >> 6, l = t & 63;
    const int g = l >> 4, lr = l & 15;
    const int wr = w >> 1, wc = w & 1;

    v4f acc[4][4];
    #pragma unroll
    for (int i = 0; i < 4; i++)
        #pragma unroll
        for (int j = 0; j < 4; j++) acc[i][j] = (v4f){0.f, 0.f, 0.f, 0.f};

    for (int kt = 0; kt < 16; ++kt) {
        const int k0 = kt * 64;
        __syncthreads();
        #pragma unroll
        for (int i = 0; i < 4; ++i) {
            int c = i * 256 + t;
            int row = c >> 3, cc = c & 7;
            gld16(A  + (size_t)(bm * 128 + row) * 1024 + k0 + cc * 8,
                  (ushort*)As + (i * 256 + w * 64) * 8);
            gld16(Bw + (size_t)(bn * 128 + row) * 1024 + k0 + cc * 8,
                  (ushort*)Bs + (i * 256 + w * 64) * 8);
        }
        __syncthreads();
        #pragma unroll
        for (int ks = 0; ks < 64; ks += 32) {
            v8s af[4], bf[4];
            #pragma unroll
            for (int i = 0; i < 4; i++) {
                af[i] = *reinterpret_cast<const v8s*>(&As[(wr * 64 + i * 16 + lr) * 64 + ks + g * 8]);
                bf[i] = *reinterpret_cast<const v8s*>(&Bs[(wc * 64 + i * 16 + lr) * 64 + ks + g * 8]);
            }
            #pragma unroll
            for (int i = 0; i < 4; i++)
                #pragma unroll
                for (int j = 0; j < 4; j++)
                    acc[i][j] = __builtin_amdgcn_mfma_f32_16x16x32_bf16(af[i], bf[j], acc[i][j], 0, 0, 0);
        }
    }

    if (MODE == 0) {
        const int region = bn >> 3;           // 0=Q 1=K 2=V
        const float scale = (region == 0) ? 0.125f : 1.0f;
        #pragma unroll
        for (int i = 0; i < 4; i++) {
            int m0 = bm * 128 + wr * 64 + i * 16 + g * 4;
            #pragma unroll
            for (int j = 0; j < 4; j++) {
                int nl = (bn & 7) * 128 + wc * 64 + j * 16 + lr;
                if (region == 2) {
                    int bb = m0 >> 11, s0 = m0 & 2047;
                    int hh = nl >> 6, dd = nl & 63;
                    ushort4 o4;
                    o4.x = f2b(acc[i][j][0]); o4.y = f2b(acc[i][j][1]);
                    o4.z = f2b(acc[i][j][2]); o4.w = f2b(acc[i][j][3]);
                    *reinterpret_cast<ushort4*>(&ov[((size_t)(bb * NH + hh) * HD + dd) * SEQ + s0]) = o4;
                } else {
                    ushort* dst = (region == 0) ? oq : ok;
                    #pragma unroll
                    for (int r = 0; r < 4; r++)
                        dst[(size_t)(m0 + r) * 1024 + nl] = f2b(acc[i][j][r] * scale);
                }
            }
        }
    } else {
        #pragma unroll
        for (int i = 0; i < 4; i++) {
            int m0 = bm * 128 + wr * 64 + i * 16 + g * 4;
            #pragma unroll
            for (int j = 0; j < 4; j++) {
                int n = bn * 128 + wc * 64 + j * 16 + lr;
                #pragma unroll
                for (int r = 0; r < 4; r++)
                    of[(size_t)(m0 + r) * 1024 + n] = acc[i][j][r];
            }
        }
    }
}

// ---------------- flash attention, swapped QK^T, software-pipelined ----------------
// Q,K: bf16 [B,S,H,D]; Vt: bf16 [B,H,D,S]; bias f32 [B,H,S,S]; mask f32 [S,S]
#define GP 72
__global__ __launch_bounds__(256) void attn_kernel(const ushort* __restrict__ Q,
                                                   const ushort* __restrict__ Kb,
                                                   const ushort* __restrict__ Vt,
                                                   const float* __restrict__ bias,
                                                   const float* __restrict__ mask,
                                                   ushort* __restrict__ O) {
    __shared__ __align__(16) ushort Ks[64 * GP];
    __shared__ __align__(16) ushort Vs[64 * GP];
    __shared__ __align__(16) ushort Ps[4][16 * GP];

    const int bh = blockIdx.x, qblk = blockIdx.y;
    const int b = bh >> 4, h = bh & 15;
    const int t = threadIdx.x, w = t >> 6, l = t & 63;
    const int lr = l & 15, g = l >> 4;
    const int qg = qblk * 64 + w * 16 + lr;

    // staging geometry: id = t + c*256 -> row = id>>3, chunk = id&7 (16B units)
    const int srow0 = t >> 3,        sch0 = t & 7;
    const int srow1 = (t + 256) >> 3, sch1 = (t + 256) & 7;

    // Q fragment (B operand): lane holds Q[qg][d0*32 + g*8 .. +8]
    v8s qf[2];
    #pragma unroll
    for (int d0 = 0; d0 < 2; ++d0)
        qf[d0] = *reinterpret_cast<const v8s*>(&Q[((size_t)(b * SEQ + qg) * NH + h) * HD + d0 * 32 + g * 8]);

    float m_run = -1e30f, l_run = 0.f;
    v4f oacc[4];
    #pragma unroll
    for (int dt = 0; dt < 4; ++dt) oacc[dt] = (v4f){0.f, 0.f, 0.f, 0.f};

    const float* bp = bias + (size_t)bh * SEQ * SEQ + (size_t)qg * SEQ;
    const float* mp = mask + (size_t)qg * SEQ;

    // ---- prologue: prefetch tile 0 (K/V into regs, bias/mask into regs) ----
    uint4 kreg0, kreg1, vreg0, vreg1;
    kreg0 = *reinterpret_cast<const uint4*>(&Kb[((size_t)(b * SEQ + srow0) * NH + h) * HD + sch0 * 8]);
    kreg1 = *reinterpret_cast<const uint4*>(&Kb[((size_t)(b * SEQ + srow1) * NH + h) * HD + sch1 * 8]);
    vreg0 = *reinterpret_cast<const uint4*>(&Vt[((size_t)bh * HD + srow0) * SEQ + sch0 * 8]);
    vreg1 = *reinterpret_cast<const uint4*>(&Vt[((size_t)bh * HD + srow1) * SEQ + sch1 * 8]);
    float4 bf[4], mf[4];
    #pragma unroll
    for (int nt = 0; nt < 4; ++nt) {
        bf[nt] = *reinterpret_cast<const float4*>(bp + nt * 16 + g * 4);
        mf[nt] = *reinterpret_cast<const float4*>(mp + nt * 16 + g * 4);
    }

    #pragma unroll 1
    for (int kt = 0; kt < 32; ++kt) {
        const int k0n = (kt + 1) * 64;   // next tile base
        __syncthreads();   // A: all waves done reading Ks/Vs of prev tile (drains prefetch vmcnt too)
        *reinterpret_cast<uint4*>(&Ks[srow0 * GP + sch0 * 8]) = kreg0;
        *reinterpret_cast<uint4*>(&Ks[srow1 * GP + sch1 * 8]) = kreg1;
        *reinterpret_cast<uint4*>(&Vs[srow0 * GP + sch0 * 8]) = vreg0;
        *reinterpret_cast<uint4*>(&Vs[srow1 * GP + sch1 * 8]) = vreg1;
        __syncthreads();   // B: tiles staged

        // issue K/V prefetch for next tile (covered by this tile's compute)
        if (kt != 31) {
            kreg0 = *reinterpret_cast<const uint4*>(&Kb[((size_t)(b * SEQ + k0n + srow0) * NH + h) * HD + sch0 * 8]);
            kreg1 = *reinterpret_cast<const uint4*>(&Kb[((size_t)(b * SEQ + k0n + srow1) * NH + h) * HD + sch1 * 8]);
            vreg0 = *reinterpret_cast<const uint4*>(&Vt[((size_t)bh * HD + srow0) * SEQ + k0n + sch0 * 8]);
            vreg1 = *reinterpret_cast<const uint4*>(&Vt[((size_t)bh * HD + srow1) * SEQ + k0n + sch1 * 8]);
        }

        // swapped QK^T: sacc[nt][r] = S[k0 + nt*16 + g*4 + r][qg]
        v4f sacc[4];
        #pragma unroll
        for (int nt = 0; nt < 4; ++nt) sacc[nt] = (v4f){0.f, 0.f, 0.f, 0.f};
        __builtin_amdgcn_s_setprio(1);
        #pragma unroll
        for (int nt = 0; nt < 4; ++nt)
            #pragma unroll
            for (int d0 = 0; d0 < 2; ++d0) {
                v8s kf = *reinterpret_cast<const v8s*>(&Ks[(nt * 16 + lr) * GP + d0 * 32 + g * 8]);
                sacc[nt] = __builtin_amdgcn_mfma_f32_16x16x32_bf16(kf, qf[d0], sacc[nt], 0, 0, 0);
            }
        __builtin_amdgcn_s_setprio(0);

        // scores += bias + mask (prefetched regs), then reissue prefetch for next tile
        float mx = -1e30f;
        #pragma unroll
        for (int nt = 0; nt < 4; ++nt) {
            sacc[nt][0] += bf[nt].x + mf[nt].x;
            sacc[nt][1] += bf[nt].y + mf[nt].y;
            sacc[nt][2] += bf[nt].z + mf[nt].z;
            sacc[nt][3] += bf[nt].w + mf[nt].w;
            mx = fmaxf(mx, fmaxf(fmaxf(sacc[nt][0], sacc[nt][1]), fmaxf(sacc[nt][2], sacc[nt][3])));
        }
        if (kt != 31) {
            #pragma unroll
            for (int nt = 0; nt < 4; ++nt) {
                bf[nt] = *reinterpret_cast<const float4*>(bp + k0n + nt * 16 + g * 4);
                mf[nt] = *reinterpret_cast<const float4*>(mp + k0n + nt * 16 + g * 4);
            }
        }

        mx = fmaxf(mx, __shfl_xor(mx, 16));
        mx = fmaxf(mx, __shfl_xor(mx, 32));
        float mnew = fmaxf(m_run, mx);
        float corr = __expf(m_run - mnew);
        m_run = mnew;
        float rs = 0.f;
        #pragma unroll
        for (int nt = 0; nt < 4; ++nt)
            #pragma unroll
            for (int r = 0; r < 4; ++r) {
                float e = __expf(sacc[nt][r] - mnew);
                sacc[nt][r] = e;
                rs += e;
            }
        rs += __shfl_xor(rs, 16);
        rs += __shfl_xor(rs, 32);
        l_run = l_run * corr + rs;
        #pragma unroll
        for (int dt = 0; dt < 4; ++dt) oacc[dt] *= corr;

        // P -> bf16 into wave-private LDS row (no barrier needed)
        #pragma unroll
        for (int nt = 0; nt < 4; ++nt) {
            unsigned lo = pk2(sacc[nt][0], sacc[nt][1]);
            unsigned hi = pk2(sacc[nt][2], sacc[nt][3]);
            *reinterpret_cast<unsigned*>(&Ps[w][lr * GP + nt * 16 + g * 4])     = lo;
            *reinterpret_cast<unsigned*>(&Ps[w][lr * GP + nt * 16 + g * 4 + 2]) = hi;
        }

        // PV: O^T[d][q] += V^T[d][k] * P[k][q]
        __builtin_amdgcn_s_setprio(1);
        #pragma unroll
        for (int c0 = 0; c0 < 2; ++c0) {
            v8s pf = *reinterpret_cast<const v8s*>(&Ps[w][lr * GP + c0 * 32 + g * 8]);
            #pragma unroll
            for (int dt = 0; dt < 4; ++dt) {
                v8s vf = *reinterpret_cast<const v8s*>(&Vs[(dt * 16 + lr) * GP + c0 * 32 + g * 8]);
                oacc[dt] = __builtin_amdgcn_mfma_f32_16x16x32_bf16(vf, pf, oacc[dt], 0, 0, 0);
            }
        }
        __builtin_amdgcn_s_setprio(0);
    }

    float inv = 1.f / l_run;
    #pragma unroll
    for (int dt = 0; dt < 4; ++dt) {
        ushort4 o4;
        o4.x = f2b(oacc[dt][0] * inv); o4.y = f2b(oacc[dt][1] * inv);
        o4.z = f2b(oacc[dt][2] * inv); o4.w = f2b(oacc[dt][3] * inv);
        *reinterpret_cast<ushort4*>(&O[((size_t)(b * SEQ + qg) * NH + h) * HD + dt * 16 + g * 4]) = o4;
    }
}

extern "C" void kernel_launch(void* const* d_in, const int* in_sizes, int n_in,
                              void* d_out, int out_size, void* d_ws, size_t ws_size,
                              hipStream_t stream) {
    (void)in_sizes; (void)n_in; (void)out_size; (void)ws_size;
    const float* x    = (const float*)d_in[0];
    const float* mask = (const float*)d_in[1];
    const float* bias = (const float*)d_in[2];
    const float* wq   = (const float*)d_in[3];
    const float* wk   = (const float*)d_in[4];
    const float* wv   = (const float*)d_in[5];
    const float* wo   = (const float*)d_in[6];
    float* out = (float*)d_out;

    ushort* xb    = (ushort*)d_ws;
    ushort* wcomb = xb    + (4 << 20);
    ushort* qb    = wcomb + (4 << 20);
    ushort* kb    = qb    + (4 << 20);
    ushort* vtb   = kb    + (4 << 20);
    ushort* ob    = vtb   + (4 << 20);

    castx<<<4096, 256, 0, stream>>>(x, xb, 1 << 22);
    castw<<<4096, 256, 0, stream>>>(wq, wk, wv, wo, wcomb);

    gemm128<0><<<dim3(32, 24), 256, 0, stream>>>(xb, wcomb, qb, kb, vtb, nullptr);

    attn_kernel<<<dim3(32, 32), 256, 0, stream>>>(qb, kb, vtb, bias, mask, ob);

    gemm128<1><<<dim3(32, 8), 256, 0, stream>>>(ob, wcomb + (size_t)3072 * 1024,
                                                nullptr, nullptr, nullptr, out);
}